// Round 3
// baseline (716.694 us; speedup 1.0000x reference)
//
#include <hip/hip_runtime.h>
#include <hip/hip_bf16.h>
#include <math.h>

typedef _Float16 f16;
typedef __attribute__((ext_vector_type(8))) _Float16 f16x8;
typedef __attribute__((ext_vector_type(4))) _Float16 f16x4;
typedef __attribute__((ext_vector_type(4))) float f32x4;

namespace {
constexpr int B = 4, L = 2048, D = 512, NH = 8, DH = 64;
}

// ---- E cast: fp32 -> fp16 (131072 elems) ----
__global__ __launch_bounds__(256)
void ecast_kernel(const float* __restrict__ E, f16* __restrict__ Ef) {
    int i4 = (blockIdx.x * 256 + threadIdx.x) * 4;
    float4 x = *(const float4*)(E + i4);
    *(f16x4*)(Ef + i4) = (f16x4){(f16)x.x, (f16)x.y, (f16)x.z, (f16)x.w};
}

// ---- W transpose+cast: W[k][n] fp32 -> Wt[sel][n][k] fp16, 64x64 tiles ----
__global__ __launch_bounds__(256)
void wtrans_kernel(const float* __restrict__ Wq, const float* __restrict__ Wk,
                   const float* __restrict__ Wv, f16* __restrict__ Wt) {
    __shared__ f16 Ws[64 * 65];
    const int sel = blockIdx.z;
    const float* W = (sel == 0) ? Wq : (sel == 1) ? Wk : Wv;
    f16* Wo = Wt + (size_t)sel * D * D;
    const int k0 = blockIdx.x * 64, n0 = blockIdx.y * 64;
    const int t = threadIdx.x;
#pragma unroll
    for (int i = 0; i < 16; ++i) {
        int idx = 256 * i + t;
        int r = idx >> 6, c = idx & 63;
        Ws[r * 65 + c] = (f16)W[(size_t)(k0 + r) * D + n0 + c];
    }
    __syncthreads();
    const int c = t >> 2, kseg = t & 3;
    f16x8 r0, r1;
#pragma unroll
    for (int j = 0; j < 8; ++j) r0[j] = Ws[(kseg * 16 + j) * 65 + c];
#pragma unroll
    for (int j = 0; j < 8; ++j) r1[j] = Ws[(kseg * 16 + 8 + j) * 65 + c];
    f16* o = Wo + (size_t)(n0 + c) * D + k0 + kseg * 16;
    *(f16x8*)o = r0;
    *(f16x8*)(o + 8) = r1;
}

// ---- fused projections: C = X(fp32) . W, fp16 MFMA single-pass ----
// Flat grid 1536, XCD-chunked swizzle, (sel,head)-major within chunk so the 8
// head-blocks sharing one 128x512 X panel run consecutively on the same XCD.
__global__ __launch_bounds__(256, 4)
void proj_gemm(const float* __restrict__ q, const float* __restrict__ k,
               const float* __restrict__ v, const f16* __restrict__ Wt,
               f16* __restrict__ Qf, f16* __restrict__ Kf, f16* __restrict__ Vtf) {
    __shared__ f16 As[128 * 72];
    __shared__ f16 Bs[64 * 72];
    const int flat = blockIdx.x;
    const int wg = (flat & 7) * 192 + (flat >> 3);   // 1536 = 8 XCDs * 192
    const int by = wg % 24, bx = wg / 24;            // by fast: heads share X panel
    const int sel = by >> 3, h = by & 7;
    const int m0 = bx * 128;
    const float* X = (sel == 0) ? q : (sel == 1) ? k : v;
    const f16* Bt = Wt + (size_t)sel * D * D + (size_t)h * 64 * D;
    const int t = threadIdx.x, wid = t >> 6, lane = t & 63;
    const int quad = lane >> 4, col = lane & 15;
    const int mw = wid * 32;

    f32x4 acc[2][4];
#pragma unroll
    for (int i = 0; i < 2; ++i)
#pragma unroll
        for (int j = 0; j < 4; ++j) acc[i][j] = (f32x4){0.f, 0.f, 0.f, 0.f};

    float4 xa[8];
    f16x8 breg[2];
    auto loadG = [&](int k0) {
#pragma unroll
        for (int i = 0; i < 8; ++i) {
            int idx = 256 * i + t;
            int r = idx >> 4, c4 = idx & 15;           // 128 rows x 16 float4
            xa[i] = *(const float4*)(X + (size_t)(m0 + r) * D + k0 + c4 * 4);
        }
#pragma unroll
        for (int i = 0; i < 2; ++i) {
            int idx = 256 * i + t;
            int r = idx >> 3, ch = idx & 7;            // 64 rows x 8 chunks
            breg[i] = *(const f16x8*)(Bt + (size_t)r * D + k0 + ch * 8);
        }
    };
    auto storeL = [&]() {
#pragma unroll
        for (int i = 0; i < 8; ++i) {
            int idx = 256 * i + t;
            int r = idx >> 4, c4 = idx & 15;
            *(f16x4*)(As + r * 72 + c4 * 4) =
                (f16x4){(f16)xa[i].x, (f16)xa[i].y, (f16)xa[i].z, (f16)xa[i].w};
        }
#pragma unroll
        for (int i = 0; i < 2; ++i) {
            int idx = 256 * i + t;
            int r = idx >> 3, ch = idx & 7;
            *(f16x8*)(Bs + r * 72 + ch * 8) = breg[i];
        }
    };

    loadG(0);
    for (int k0 = 0; k0 < D; k0 += 64) {
        __syncthreads();
        storeL();
        __syncthreads();
        if (k0 + 64 < D) loadG(k0 + 64);
#pragma unroll
        for (int ks = 0; ks < 2; ++ks) {
            f16x8 af[2], bf[4];
#pragma unroll
            for (int mt = 0; mt < 2; ++mt)
                af[mt] = *(const f16x8*)(As + (mw + mt * 16 + col) * 72 + quad * 8 + ks * 32);
#pragma unroll
            for (int nt = 0; nt < 4; ++nt)
                bf[nt] = *(const f16x8*)(Bs + (nt * 16 + col) * 72 + quad * 8 + ks * 32);
#pragma unroll
            for (int mt = 0; mt < 2; ++mt)
#pragma unroll
                for (int nt = 0; nt < 4; ++nt)
                    acc[mt][nt] = __builtin_amdgcn_mfma_f32_16x16x32_f16(af[mt], bf[nt], acc[mt][nt], 0, 0, 0);
        }
    }

    if (sel < 2) {
        f16* Y = (sel == 0) ? Qf : Kf;
#pragma unroll
        for (int mt = 0; mt < 2; ++mt)
#pragma unroll
            for (int nt = 0; nt < 4; ++nt)
#pragma unroll
                for (int reg = 0; reg < 4; ++reg) {
                    int m = m0 + mw + mt * 16 + quad * 4 + reg;
                    int bb = m >> 11, l = m & 2047, d = nt * 16 + col;
                    Y[((size_t)(bb * NH + h) * L + l) * DH + d] = (f16)acc[mt][nt][reg];
                }
    } else {
        __syncthreads();                 // As frag reads done; reuse as Cs[64][136]
        f16* Cs = As;
#pragma unroll
        for (int mt = 0; mt < 2; ++mt)
#pragma unroll
            for (int nt = 0; nt < 4; ++nt)
#pragma unroll
                for (int reg = 0; reg < 4; ++reg) {
                    int d = nt * 16 + col;
                    int lc = mw + mt * 16 + quad * 4 + reg;
                    Cs[d * 136 + lc] = (f16)acc[mt][nt][reg];
                }
        __syncthreads();
        const int dd = t >> 2, seg = t & 3;
        const int bb = m0 >> 11, l0 = m0 & 2047;
        f16* Yv = Vtf + ((size_t)(bb * NH + h) * DH + dd) * L + l0 + seg * 32;
#pragma unroll
        for (int j = 0; j < 4; ++j)
            *(f16x8*)(Yv + j * 8) = *(const f16x8*)(Cs + dd * 136 + seg * 32 + j * 8);
    }
}

// ---- flash attention: BARRIER-FREE, K/V fragments direct from L1/L2 ----
// No cross-wave LDS sharing -> no __syncthreads. Each wave streams its own
// K-tile (register-prefetched one tile ahead) and V-tile (issued right after
// QK^T, drains under Srel+softmax). Pbuf is wave-private (lgkmcnt-ordered).
// XCD-chunked flat grid: 128 consecutive wg per XCD = 4 head-groups, so each
// XCD's L2 holds its 4 heads' K+V (2MB) + Q + E.
__global__ __launch_bounds__(256, 4)
void attn_kernel(const f16* __restrict__ Qf, const f16* __restrict__ Kf,
                 const f16* __restrict__ Vtf, const f16* __restrict__ Ef,
                 float* __restrict__ out) {
    __shared__ __align__(16) f16 Pbuf[4][16 * 72];

    const int t = threadIdx.x, wid = t >> 6, lane = t & 63;
    const int quad = lane >> 4, col = lane & 15;
    const int flat = blockIdx.x;
    const int wg = (flat & 7) * 128 + (flat >> 3);   // 1024 = 8 XCDs * 128
    const int xq = wg & 31, yz = wg >> 5;
    const int h = yz & 7, bb = yz >> 3;
    const int l0w = xq * 64 + wid * 16;
    const size_t head = (size_t)(bb * NH + h) * (size_t)(L * DH);
    const f16* qf = Qf + head;
    const f16* kf = Kf + head;
    const f16* vt = Vtf + head;      // [dh][L]
    f16* Pw = Pbuf[wid];

    f16x8 qF[2], qS[2];
    {
        const int m = l0w + col;
        const int mS = min(m + 1, L - 1);   // row L never actually used
#pragma unroll
        for (int ks = 0; ks < 2; ++ks) {
            const int off = quad * 8 + ks * 32;
            qF[ks] = *(const f16x8*)(qf + (size_t)m * DH + off);
            qS[ks] = *(const f16x8*)(qf + (size_t)mS * DH + off);
        }
    }

    f16x8 kfr[4][2], vfr[4][2];
    auto loadK = [&](int c0) {
        const f16* kb = kf + (size_t)(c0 + col) * DH + quad * 8;
#pragma unroll
        for (int ns = 0; ns < 4; ++ns)
#pragma unroll
            for (int ks = 0; ks < 2; ++ks)
                kfr[ns][ks] = *(const f16x8*)(kb + (size_t)(ns * 16) * DH + ks * 32);
    };
    auto loadV = [&](int c0) {
        const f16* vb = vt + (size_t)col * L + c0 + quad * 8;
#pragma unroll
        for (int ns = 0; ns < 4; ++ns)
#pragma unroll
            for (int ks = 0; ks < 2; ++ks)
                vfr[ns][ks] = *(const f16x8*)(vb + (size_t)(ns * 16) * L + ks * 32);
    };

    f32x4 O[4];
#pragma unroll
    for (int i = 0; i < 4; ++i) O[i] = (f32x4){0.f, 0.f, 0.f, 0.f};
    float mrow[4] = {-1e30f, -1e30f, -1e30f, -1e30f};
    float srow[4] = {0.f, 0.f, 0.f, 0.f};

    loadK(0);
    for (int c0 = 0; c0 < L; c0 += 64) {
        const int d0 = c0 - l0w;

        // ---- S = Q K^T from prefetched K fragments ----
        f32x4 S[4];
        __builtin_amdgcn_s_setprio(1);
#pragma unroll
        for (int ns = 0; ns < 4; ++ns) {
            S[ns] = (f32x4){0.f, 0.f, 0.f, 0.f};
#pragma unroll
            for (int ks = 0; ks < 2; ++ks)
                S[ns] = __builtin_amdgcn_mfma_f32_16x16x32_f16(qF[ks], kfr[ns][ks], S[ns], 0, 0, 0);
        }
        __builtin_amdgcn_s_setprio(0);

        // issue this tile's V loads + next tile's K loads; they drain under
        // Srel + softmax compute
        loadV(c0);
        loadK((c0 + 64 < L) ? c0 + 64 : c0);

        // ---- Srel: G = Q . E-window^T, scatter via intra-quad shuffles ----
        const bool doA = (d0 <= 15);
        const bool doB = (d0 >= -61);
#pragma unroll 1
        for (int pass = 0; pass < 2; ++pass) {
            if ((pass == 0 && !doA) || (pass == 1 && !doB)) continue;
            const int jbase = (pass == 0) ? (d0 + L - 16) : (d0 - 17);
            f32x4 G[5];
#pragma unroll
            for (int g = 0; g < 5; ++g) {
                int er = min(max(jbase + g * 16 + col, 0), L - 1);
                G[g] = (f32x4){0.f, 0.f, 0.f, 0.f};
                const size_t eb = (size_t)er * DH + quad * 8;
#pragma unroll
                for (int ks = 0; ks < 2; ++ks) {
                    f16x8 e8 = *(const f16x8*)(Ef + eb + ks * 32);
                    G[g] = __builtin_amdgcn_mfma_f32_16x16x32_f16(
                               (pass == 0) ? qF[ks] : qS[ks], e8, G[g], 0, 0, 0);
                }
            }
#pragma unroll
            for (int reg = 0; reg < 4; ++reg) {
                const int r  = quad * 4 + reg;
                const int jj = col - r + 15;            // [0,30]
                const int src = quad * 16 + (jj & 15);  // same quad holds row r
#pragma unroll
                for (int ns = 0; ns < 4; ++ns) {
                    float v0 = __shfl(G[ns][reg], src, 64);
                    float v1 = __shfl(G[ns + 1][reg], src, 64);
                    float val = (jj < 16) ? v0 : v1;
                    const int rel = d0 + ns * 16 + col - r;
                    const bool use = (pass == 0) ? (rel <= 0) : (rel >= 2);
                    if (use) S[ns][reg] += val;
                }
            }
        }

        // ---- online softmax (rows in 16-lane groups) ----
#pragma unroll
        for (int reg = 0; reg < 4; ++reg) {
            float tm = fmaxf(fmaxf(S[0][reg], S[1][reg]), fmaxf(S[2][reg], S[3][reg]));
#pragma unroll
            for (int msk = 1; msk < 16; msk <<= 1)
                tm = fmaxf(tm, __shfl_xor(tm, msk, 16));
            const float mnew  = fmaxf(mrow[reg], tm);
            const float alpha = __expf(mrow[reg] - mnew);
            float p[4], ps = 0.f;
#pragma unroll
            for (int ns = 0; ns < 4; ++ns) { p[ns] = __expf(S[ns][reg] - mnew); ps += p[ns]; }
#pragma unroll
            for (int msk = 1; msk < 16; msk <<= 1)
                ps += __shfl_xor(ps, msk, 16);
            srow[reg] = srow[reg] * alpha + ps;
            mrow[reg] = mnew;
            const int r = quad * 4 + reg;
#pragma unroll
            for (int ns = 0; ns < 4; ++ns) {
                O[ns][reg] *= alpha;
                Pw[r * 72 + ns * 16 + col] = (f16)p[ns];
            }
        }
        // wave-private Pw write->read ordered by lgkmcnt within the wave

        // ---- O += P V ----
        f16x8 pA[2];
        pA[0] = *(const f16x8*)(Pw + col * 72 + quad * 8);
        pA[1] = *(const f16x8*)(Pw + col * 72 + 32 + quad * 8);
        __builtin_amdgcn_s_setprio(1);
#pragma unroll
        for (int ns = 0; ns < 4; ++ns) {
#pragma unroll
            for (int ks = 0; ks < 2; ++ks)
                O[ns] = __builtin_amdgcn_mfma_f32_16x16x32_f16(pA[ks], vfr[ns][ks], O[ns], 0, 0, 0);
        }
        __builtin_amdgcn_s_setprio(0);
    }

#pragma unroll
    for (int reg = 0; reg < 4; ++reg) {
        const int l = l0w + quad * 4 + reg;
        const float inv = 1.0f / (srow[reg] * 8.0f);
        float* o = out + ((size_t)bb * L + l) * D + h * DH;
#pragma unroll
        for (int ns = 0; ns < 4; ++ns)
            o[ns * 16 + col] = O[ns][reg] * inv;
    }
}

extern "C" void kernel_launch(void* const* d_in, const int* in_sizes, int n_in,
                              void* d_out, int out_size, void* d_ws, size_t ws_size,
                              hipStream_t stream) {
    const float* q  = (const float*)d_in[0];
    const float* k  = (const float*)d_in[1];
    const float* v  = (const float*)d_in[2];
    const float* Wq = (const float*)d_in[3];
    const float* Wk = (const float*)d_in[4];
    const float* Wv = (const float*)d_in[5];
    const float* E  = (const float*)d_in[6];
    float* out = (float*)d_out;

    // ws (fp16 elems): Qf | Kf | Vtf (4M each) | Wt (3x256K) | Ef (128K) = ~27 MB
    const size_t plane = (size_t)B * NH * L * DH;
    f16* Qf  = (f16*)d_ws;
    f16* Kfp = Qf + plane;
    f16* Vtf = Kfp + plane;
    f16* Wt  = Vtf + plane;
    f16* Ef  = Wt + (size_t)3 * D * D;

    ecast_kernel<<<L * DH / 1024, 256, 0, stream>>>(E, Ef);
    wtrans_kernel<<<dim3(8, 8, 3), 256, 0, stream>>>(Wq, Wk, Wv, Wt);
    proj_gemm<<<dim3(1536), 256, 0, stream>>>(q, k, v, Wt, Qf, Kfp, Vtf);
    attn_kernel<<<dim3(1024), 256, 0, stream>>>(Qf, Kfp, Vtf, Ef, out);
}

// Round 4
// 324.385 us; speedup vs baseline: 2.2094x; 2.2094x over previous
//
#include <hip/hip_runtime.h>
#include <hip/hip_bf16.h>
#include <math.h>

typedef _Float16 f16;
typedef __attribute__((ext_vector_type(8))) _Float16 f16x8;
typedef __attribute__((ext_vector_type(4))) _Float16 f16x4;
typedef __attribute__((ext_vector_type(4))) float f32x4;

namespace {
constexpr int B = 4, L = 2048, D = 512, NH = 8, DH = 64;
}

__device__ __forceinline__ float dpp_xor1(float x) {   // lane ^= 1 (quad_perm 1,0,3,2)
    return __int_as_float(__builtin_amdgcn_update_dpp(0, __float_as_int(x), 0xB1, 0xF, 0xF, true));
}
__device__ __forceinline__ float dpp_xor2(float x) {   // lane ^= 2 (quad_perm 2,3,0,1)
    return __int_as_float(__builtin_amdgcn_update_dpp(0, __float_as_int(x), 0x4E, 0xF, 0xF, true));
}

// ---- E cast: fp32 -> fp16 (131072 elems) ----
__global__ __launch_bounds__(256)
void ecast_kernel(const float* __restrict__ E, f16* __restrict__ Ef) {
    int i4 = (blockIdx.x * 256 + threadIdx.x) * 4;
    float4 x = *(const float4*)(E + i4);
    *(f16x4*)(Ef + i4) = (f16x4){(f16)x.x, (f16)x.y, (f16)x.z, (f16)x.w};
}

// ---- X cast: q/k/v fp32 -> f16 planes (halves proj's re-fetch traffic) ----
__global__ __launch_bounds__(256)
void xcast_kernel(const float* __restrict__ q, const float* __restrict__ k,
                  const float* __restrict__ v, f16* __restrict__ Xf) {
    const int sel = blockIdx.y;
    const float* X = (sel == 0) ? q : (sel == 1) ? k : v;
    const size_t i4 = ((size_t)blockIdx.x * 256 + threadIdx.x) * 4;
    float4 x = *(const float4*)(X + i4);
    *(f16x4*)(Xf + (size_t)sel * ((size_t)B * L * D) + i4) =
        (f16x4){(f16)x.x, (f16)x.y, (f16)x.z, (f16)x.w};
}

// ---- W transpose+cast: W[k][n] fp32 -> Wt[sel][n][k] fp16, 64x64 tiles ----
__global__ __launch_bounds__(256)
void wtrans_kernel(const float* __restrict__ Wq, const float* __restrict__ Wk,
                   const float* __restrict__ Wv, f16* __restrict__ Wt) {
    __shared__ f16 Ws[64 * 65];
    const int sel = blockIdx.z;
    const float* W = (sel == 0) ? Wq : (sel == 1) ? Wk : Wv;
    f16* Wo = Wt + (size_t)sel * D * D;
    const int k0 = blockIdx.x * 64, n0 = blockIdx.y * 64;
    const int t = threadIdx.x;
#pragma unroll
    for (int i = 0; i < 16; ++i) {
        int idx = 256 * i + t;
        int r = idx >> 6, c = idx & 63;
        Ws[r * 65 + c] = (f16)W[(size_t)(k0 + r) * D + n0 + c];
    }
    __syncthreads();
    const int c = t >> 2, kseg = t & 3;
    f16x8 r0, r1;
#pragma unroll
    for (int j = 0; j < 8; ++j) r0[j] = Ws[(kseg * 16 + j) * 65 + c];
#pragma unroll
    for (int j = 0; j < 8; ++j) r1[j] = Ws[(kseg * 16 + 8 + j) * 65 + c];
    f16* o = Wo + (size_t)(n0 + c) * D + k0 + kseg * 16;
    *(f16x8*)o = r0;
    *(f16x8*)(o + 8) = r1;
}

// ---- fused projections: C = Xf(f16) . W, fp16 MFMA single-pass ----
// Flat grid 1536, XCD-chunked swizzle, (sel,head)-major within chunk so the 8
// head-blocks sharing one 128x512 X panel run consecutively on the same XCD.
// A staging is now a pure f16 copy (no cvt in the hot loop).
__global__ __launch_bounds__(256, 4)
void proj_gemm(const f16* __restrict__ Xf, const f16* __restrict__ Wt,
               f16* __restrict__ Qf, f16* __restrict__ Kf, f16* __restrict__ Vtf) {
    __shared__ f16 As[128 * 72];
    __shared__ f16 Bs[64 * 72];
    const int flat = blockIdx.x;
    const int wg = (flat & 7) * 192 + (flat >> 3);   // 1536 = 8 XCDs * 192
    const int by = wg % 24, bx = wg / 24;            // by fast: heads share X panel
    const int sel = by >> 3, h = by & 7;
    const int m0 = bx * 128;
    const f16* X = Xf + (size_t)sel * ((size_t)B * L * D);
    const f16* Bt = Wt + (size_t)sel * D * D + (size_t)h * 64 * D;
    const int t = threadIdx.x, wid = t >> 6, lane = t & 63;
    const int quad = lane >> 4, col = lane & 15;
    const int mw = wid * 32;

    f32x4 acc[2][4];
#pragma unroll
    for (int i = 0; i < 2; ++i)
#pragma unroll
        for (int j = 0; j < 4; ++j) acc[i][j] = (f32x4){0.f, 0.f, 0.f, 0.f};

    f16x8 xa[4];
    f16x8 breg[2];
    auto loadG = [&](int k0) {
#pragma unroll
        for (int i = 0; i < 4; ++i) {
            int idx = 256 * i + t;
            int r = idx >> 3, ch = idx & 7;            // 128 rows x 8 chunks
            xa[i] = *(const f16x8*)(X + (size_t)(m0 + r) * D + k0 + ch * 8);
        }
#pragma unroll
        for (int i = 0; i < 2; ++i) {
            int idx = 256 * i + t;
            int r = idx >> 3, ch = idx & 7;            // 64 rows x 8 chunks
            breg[i] = *(const f16x8*)(Bt + (size_t)r * D + k0 + ch * 8);
        }
    };
    auto storeL = [&]() {
#pragma unroll
        for (int i = 0; i < 4; ++i) {
            int idx = 256 * i + t;
            int r = idx >> 3, ch = idx & 7;
            *(f16x8*)(As + r * 72 + ch * 8) = xa[i];
        }
#pragma unroll
        for (int i = 0; i < 2; ++i) {
            int idx = 256 * i + t;
            int r = idx >> 3, ch = idx & 7;
            *(f16x8*)(Bs + r * 72 + ch * 8) = breg[i];
        }
    };

    loadG(0);
    for (int k0 = 0; k0 < D; k0 += 64) {
        __syncthreads();
        storeL();
        __syncthreads();
        if (k0 + 64 < D) loadG(k0 + 64);
#pragma unroll
        for (int ks = 0; ks < 2; ++ks) {
            f16x8 af[2], bf[4];
#pragma unroll
            for (int mt = 0; mt < 2; ++mt)
                af[mt] = *(const f16x8*)(As + (mw + mt * 16 + col) * 72 + quad * 8 + ks * 32);
#pragma unroll
            for (int nt = 0; nt < 4; ++nt)
                bf[nt] = *(const f16x8*)(Bs + (nt * 16 + col) * 72 + quad * 8 + ks * 32);
#pragma unroll
            for (int mt = 0; mt < 2; ++mt)
#pragma unroll
                for (int nt = 0; nt < 4; ++nt)
                    acc[mt][nt] = __builtin_amdgcn_mfma_f32_16x16x32_f16(af[mt], bf[nt], acc[mt][nt], 0, 0, 0);
        }
    }

    if (sel < 2) {
        f16* Y = (sel == 0) ? Qf : Kf;
#pragma unroll
        for (int mt = 0; mt < 2; ++mt)
#pragma unroll
            for (int nt = 0; nt < 4; ++nt)
#pragma unroll
                for (int reg = 0; reg < 4; ++reg) {
                    int m = m0 + mw + mt * 16 + quad * 4 + reg;
                    int bb = m >> 11, l = m & 2047, d = nt * 16 + col;
                    Y[((size_t)(bb * NH + h) * L + l) * DH + d] = (f16)acc[mt][nt][reg];
                }
    } else {
        __syncthreads();                 // As frag reads done; reuse as Cs[64][136]
        f16* Cs = As;
#pragma unroll
        for (int mt = 0; mt < 2; ++mt)
#pragma unroll
            for (int nt = 0; nt < 4; ++nt)
#pragma unroll
                for (int reg = 0; reg < 4; ++reg) {
                    int d = nt * 16 + col;
                    int lc = mw + mt * 16 + quad * 4 + reg;
                    Cs[d * 136 + lc] = (f16)acc[mt][nt][reg];
                }
        __syncthreads();
        const int dd = t >> 2, seg = t & 3;
        const int bb = m0 >> 11, l0 = m0 & 2047;
        f16* Yv = Vtf + ((size_t)(bb * NH + h) * DH + dd) * L + l0 + seg * 32;
#pragma unroll
        for (int j = 0; j < 4; ++j)
            *(f16x8*)(Yv + j * 8) = *(const f16x8*)(Cs + dd * 136 + seg * 32 + j * 8);
    }
}

// ---- flash attention, fp16 MFMA, reg-prefetch K/V pipeline (R0 base) ----
// Changes vs 245us baseline:
//  * softmax denominator via MFMA against a ones-fragment (removes the
//    4-level x 4-reg shfl sum tree; sacc rescaled by alpha like O)
//  * max tree: xor1/xor2 levels via DPP quad_perm (VALU, no LDS pipe)
//  * s_setprio(1) around pure-MFMA clusters (T5)
__global__ __launch_bounds__(256, 4)
void attn_kernel(const f16* __restrict__ Qf, const f16* __restrict__ Kf,
                 const f16* __restrict__ Vtf, const f16* __restrict__ Ef,
                 float* __restrict__ out) {
    __shared__ f16 KfS[64 * 72];
    __shared__ f16 VfS[64 * 72];
    __shared__ f16 Pbuf[4][16 * 72];

    const int t = threadIdx.x, wid = t >> 6, lane = t & 63;
    const int quad = lane >> 4, col = lane & 15;
    const int l0w = blockIdx.x * 64 + wid * 16;
    const int h = blockIdx.y, bb = blockIdx.z;
    const size_t head = (size_t)(bb * NH + h) * (size_t)(L * DH);
    const f16* qf = Qf + head;
    const f16* kf = Kf + head;
    const f16* vt = Vtf + head;      // [dh][L]
    f16* Pw = Pbuf[wid];

    const f16x8 ones8 = {(f16)1.f, (f16)1.f, (f16)1.f, (f16)1.f,
                         (f16)1.f, (f16)1.f, (f16)1.f, (f16)1.f};

    f16x8 qF[2], qS[2];
    {
        const int m = l0w + col;
        const int mS = min(m + 1, L - 1);   // row L never actually used
#pragma unroll
        for (int ks = 0; ks < 2; ++ks) {
            const int off = quad * 8 + ks * 32;
            qF[ks] = *(const f16x8*)(qf + (size_t)m * DH + off);
            qS[ks] = *(const f16x8*)(qf + (size_t)mS * DH + off);
        }
    }

    f16x8 kreg[2], vreg[2];
    auto loadKV = [&](int c0) {
#pragma unroll
        for (int i = 0; i < 2; ++i) {
            int idx = 256 * i + t;
            int r = idx >> 3, ch = idx & 7;
            kreg[i] = *(const f16x8*)(kf + (size_t)(c0 + r) * DH + ch * 8);
            vreg[i] = *(const f16x8*)(vt + (size_t)r * L + c0 + ch * 8);
        }
    };

    f32x4 O[4];
#pragma unroll
    for (int i = 0; i < 4; ++i) O[i] = (f32x4){0.f, 0.f, 0.f, 0.f};
    f32x4 sacc = (f32x4){0.f, 0.f, 0.f, 0.f};
    float mrow[4] = {-1e30f, -1e30f, -1e30f, -1e30f};

    loadKV(0);
    for (int c0 = 0; c0 < L; c0 += 64) {
        __syncthreads();   // all waves done reading previous K/V tile
#pragma unroll
        for (int i = 0; i < 2; ++i) {
            int idx = 256 * i + t;
            int r = idx >> 3, ch = idx & 7;
            *(f16x8*)(KfS + r * 72 + ch * 8) = kreg[i];
            *(f16x8*)(VfS + r * 72 + ch * 8) = vreg[i];
        }
        __syncthreads();
        if (c0 + 64 < L) loadKV(c0 + 64);   // prefetch; drains behind this tile's compute

        const int d0 = c0 - l0w;

        // ---- S = Q K^T (fp16 single pass) ----
        f32x4 S[4];
        __builtin_amdgcn_s_setprio(1);
#pragma unroll
        for (int ns = 0; ns < 4; ++ns) {
            S[ns] = (f32x4){0.f, 0.f, 0.f, 0.f};
#pragma unroll
            for (int ks = 0; ks < 2; ++ks) {
                f16x8 bh = *(const f16x8*)(KfS + (ns * 16 + col) * 72 + quad * 8 + ks * 32);
                S[ns] = __builtin_amdgcn_mfma_f32_16x16x32_f16(qF[ks], bh, S[ns], 0, 0, 0);
            }
        }
        __builtin_amdgcn_s_setprio(0);

        // ---- Srel: G = Q . E-window^T, scatter via intra-quad shuffles ----
        const bool doA = (d0 <= 15);
        const bool doB = (d0 >= -61);
#pragma unroll 1
        for (int pass = 0; pass < 2; ++pass) {
            if ((pass == 0 && !doA) || (pass == 1 && !doB)) continue;
            const int jbase = (pass == 0) ? (d0 + L - 16) : (d0 - 17);
            f32x4 G[5];
#pragma unroll
            for (int g = 0; g < 5; ++g) {
                int er = min(max(jbase + g * 16 + col, 0), L - 1);
                G[g] = (f32x4){0.f, 0.f, 0.f, 0.f};
                const size_t eb = (size_t)er * DH + quad * 8;
#pragma unroll
                for (int ks = 0; ks < 2; ++ks) {
                    f16x8 e8 = *(const f16x8*)(Ef + eb + ks * 32);
                    G[g] = __builtin_amdgcn_mfma_f32_16x16x32_f16(
                               (pass == 0) ? qF[ks] : qS[ks], e8, G[g], 0, 0, 0);
                }
            }
#pragma unroll
            for (int reg = 0; reg < 4; ++reg) {
                const int r  = quad * 4 + reg;
                const int jj = col - r + 15;            // [0,30]
                const int src = quad * 16 + (jj & 15);  // same quad holds row r
#pragma unroll
                for (int ns = 0; ns < 4; ++ns) {
                    float v0 = __shfl(G[ns][reg], src, 64);
                    float v1 = __shfl(G[ns + 1][reg], src, 64);
                    float val = (jj < 16) ? v0 : v1;
                    const int rel = d0 + ns * 16 + col - r;
                    const bool use = (pass == 0) ? (rel <= 0) : (rel >= 2);
                    if (use) S[ns][reg] += val;
                }
            }
        }

        // ---- online softmax (rows in 16-lane groups); sum via MFMA below ----
#pragma unroll
        for (int reg = 0; reg < 4; ++reg) {
            float tm = fmaxf(fmaxf(S[0][reg], S[1][reg]), fmaxf(S[2][reg], S[3][reg]));
            tm = fmaxf(tm, dpp_xor1(tm));
            tm = fmaxf(tm, dpp_xor2(tm));
            tm = fmaxf(tm, __shfl_xor(tm, 4, 16));
            tm = fmaxf(tm, __shfl_xor(tm, 8, 16));
            const float mnew  = fmaxf(mrow[reg], tm);
            const float alpha = __expf(mrow[reg] - mnew);
            mrow[reg] = mnew;
            sacc[reg] *= alpha;
            const int r = quad * 4 + reg;
#pragma unroll
            for (int ns = 0; ns < 4; ++ns) {
                float p = __expf(S[ns][reg] - mnew);
                O[ns][reg] *= alpha;
                Pw[r * 72 + ns * 16 + col] = (f16)p;
            }
        }
        // wave-private Pw write->read ordered by lgkmcnt within the wave

        // ---- O += P V ; sacc += rowsum(P) via ones-fragment ----
        f16x8 pA[2];
        pA[0] = *(const f16x8*)(Pw + col * 72 + quad * 8);
        pA[1] = *(const f16x8*)(Pw + col * 72 + 32 + quad * 8);
        __builtin_amdgcn_s_setprio(1);
        sacc = __builtin_amdgcn_mfma_f32_16x16x32_f16(pA[0], ones8, sacc, 0, 0, 0);
        sacc = __builtin_amdgcn_mfma_f32_16x16x32_f16(pA[1], ones8, sacc, 0, 0, 0);
#pragma unroll
        for (int ns = 0; ns < 4; ++ns) {
#pragma unroll
            for (int ks = 0; ks < 2; ++ks) {
                f16x8 v8 = *(const f16x8*)(VfS + (ns * 16 + col) * 72 + quad * 8 + ks * 32);
                O[ns] = __builtin_amdgcn_mfma_f32_16x16x32_f16(pA[ks], v8, O[ns], 0, 0, 0);
            }
        }
        __builtin_amdgcn_s_setprio(0);
    }

#pragma unroll
    for (int reg = 0; reg < 4; ++reg) {
        const int l = l0w + quad * 4 + reg;
        const float inv = 1.0f / (sacc[reg] * 8.0f);
        float* o = out + ((size_t)bb * L + l) * D + h * DH;
#pragma unroll
        for (int ns = 0; ns < 4; ++ns)
            o[ns * 16 + col] = O[ns][reg] * inv;
    }
}

extern "C" void kernel_launch(void* const* d_in, const int* in_sizes, int n_in,
                              void* d_out, int out_size, void* d_ws, size_t ws_size,
                              hipStream_t stream) {
    const float* q  = (const float*)d_in[0];
    const float* k  = (const float*)d_in[1];
    const float* v  = (const float*)d_in[2];
    const float* Wq = (const float*)d_in[3];
    const float* Wk = (const float*)d_in[4];
    const float* Wv = (const float*)d_in[5];
    const float* E  = (const float*)d_in[6];
    float* out = (float*)d_out;

    // ws (fp16 elems): Qf|Kf|Vtf (4M each) | Wt (768K) | Ef (128K) | Xf (12M) ~ 50MB
    const size_t plane = (size_t)B * NH * L * DH;    // 4,194,304 (= B*L*D)
    f16* Qf  = (f16*)d_ws;
    f16* Kfp = Qf + plane;
    f16* Vtf = Kfp + plane;
    f16* Wt  = Vtf + plane;
    f16* Ef  = Wt + (size_t)3 * D * D;
    f16* Xf  = Ef + (size_t)L * DH;

    ecast_kernel<<<L * DH / 1024, 256, 0, stream>>>(E, Ef);
    xcast_kernel<<<dim3((unsigned)(plane / 1024), 3), 256, 0, stream>>>(q, k, v, Xf);
    wtrans_kernel<<<dim3(8, 8, 3), 256, 0, stream>>>(Wq, Wk, Wv, Wt);
    proj_gemm<<<dim3(1536), 256, 0, stream>>>(Xf, Wt, Qf, Kfp, Vtf);
    attn_kernel<<<dim3(L / 64, NH, B), 256, 0, stream>>>(Qf, Kfp, Vtf, Ef, out);
}